// Round 1
// baseline (184.767 us; speedup 1.0000x reference)
//
#include <hip/hip_runtime.h>
#include <math.h>

#define NPTS 8192
#define DDIM 128
#define LDA  72   // LDS row stride in bf16 elems: 64 data + 8 pad -> 144B rows (16B aligned, 2-way banks)

using short8 = __attribute__((ext_vector_type(8))) short;
using f32x4  = __attribute__((ext_vector_type(4))) float;

__device__ __forceinline__ unsigned short f2bf(float f) {
    // round-to-nearest-even fp32 -> bf16 (inputs are finite normals; no NaN path needed)
    unsigned int u = __float_as_uint(f);
    u += 0x7fffu + ((u >> 16) & 1u);
    return (unsigned short)(u >> 16);
}
__device__ __forceinline__ float bf2f(unsigned short s) {
    return __uint_as_float(((unsigned int)s) << 16);
}

// --- kernel 1: sq[i] = ||bf16(x_i)||^2 (consistent with the bf16 Gram) ---
__global__ void sq_kernel(const float* __restrict__ X, float* __restrict__ sq) {
    int i = blockIdx.x * blockDim.x + threadIdx.x;
    if (i >= NPTS) return;
    const float4* row = (const float4*)(X + (size_t)i * DDIM);
    float s = 0.f;
#pragma unroll
    for (int k = 0; k < DDIM / 4; ++k) {
        float4 v = row[k];
        float a = bf2f(f2bf(v.x)), b = bf2f(f2bf(v.y));
        float c = bf2f(f2bf(v.z)), d = bf2f(f2bf(v.w));
        s += a * a + b * b + c * c + d * d;
    }
    sq[i] = s;
}

// --- kernel 2: 128x128 Gram tiles via bf16 MFMA, fused loss reduction ---
__global__ __launch_bounds__(256) void pair_kernel(
    const float* __restrict__ X, const int* __restrict__ lab,
    const float* __restrict__ sq,
    float* __restrict__ posSum, float* __restrict__ negSum,
    unsigned int* __restrict__ posCnt)
{
    const int bj = blockIdx.x;  // column block
    const int bi = blockIdx.y;  // row block
    if (bj < bi) return;        // upper triangle only; off-diagonal weighted x2

    __shared__ unsigned short sA[128 * LDA];
    __shared__ unsigned short sB[128 * LDA];
    __shared__ float sSqA[128], sSqB[128];
    __shared__ int   sLabA[128], sLabB[128];
    __shared__ float rP[4], rN[4];
    __shared__ int   rC[4];

    const int tid   = threadIdx.x;
    const int rowA0 = bi * 128;
    const int rowB0 = bj * 128;

    if (tid < 128) {
        sSqA[tid]  = sq[rowA0 + tid];
        sLabA[tid] = lab[rowA0 + tid];
    } else {
        int t = tid - 128;
        sSqB[t]  = sq[rowB0 + t];
        sLabB[t] = lab[rowB0 + t];
    }

    const int wave = tid >> 6, lane = tid & 63;
    const int quad = lane >> 4, rr = lane & 15;
    const int wr = wave >> 1, wc = wave & 1;  // 64x64 quadrant per wave

    f32x4 acc[4][4];
#pragma unroll
    for (int i = 0; i < 4; ++i)
#pragma unroll
        for (int j = 0; j < 4; ++j)
            acc[i][j] = (f32x4){0.f, 0.f, 0.f, 0.f};

    // K = 128 in two chunks of 64
    for (int c = 0; c < 2; ++c) {
        __syncthreads();  // protect LDS from previous iteration's readers
        // stage A and B chunks: 128 rows x 64 cols fp32 -> bf16, coalesced float4 loads
#pragma unroll
        for (int i = 0; i < 8; ++i) {
            int f  = tid + i * 256;        // float4 index in [0, 2048)
            int r  = f >> 4, c4 = f & 15;  // row, float4-within-row
            float4 v = *(const float4*)(X + (size_t)(rowA0 + r) * DDIM + c * 64 + c4 * 4);
            ushort4 p = make_ushort4(f2bf(v.x), f2bf(v.y), f2bf(v.z), f2bf(v.w));
            *(ushort4*)&sA[r * LDA + c4 * 4] = p;
        }
#pragma unroll
        for (int i = 0; i < 8; ++i) {
            int f  = tid + i * 256;
            int r  = f >> 4, c4 = f & 15;
            float4 v = *(const float4*)(X + (size_t)(rowB0 + r) * DDIM + c * 64 + c4 * 4);
            ushort4 p = make_ushort4(f2bf(v.x), f2bf(v.y), f2bf(v.z), f2bf(v.w));
            *(ushort4*)&sB[r * LDA + c4 * 4] = p;
        }
        __syncthreads();

#pragma unroll
        for (int ks = 0; ks < 2; ++ks) {
            short8 a[4], b[4];
#pragma unroll
            for (int t = 0; t < 4; ++t)
                a[t] = *(const short8*)&sA[(wr * 64 + t * 16 + rr) * LDA + ks * 32 + quad * 8];
#pragma unroll
            for (int t = 0; t < 4; ++t)
                b[t] = *(const short8*)&sB[(wc * 64 + t * 16 + rr) * LDA + ks * 32 + quad * 8];
#pragma unroll
            for (int i = 0; i < 4; ++i)
#pragma unroll
                for (int j = 0; j < 4; ++j)
                    acc[i][j] = __builtin_amdgcn_mfma_f32_16x16x32_bf16(a[i], b[j], acc[i][j], 0, 0, 0);
        }
    }

    // epilogue: per accumulator element, dist_sq + pos/neg contribution
    // C/D layout (verified m89/m91): col = lane&15, row = quad*4 + reg
    float posS = 0.f, negS = 0.f;
    int cnt = 0;
#pragma unroll
    for (int i = 0; i < 4; ++i) {
#pragma unroll
        for (int rg = 0; rg < 4; ++rg) {
            int   rl = wr * 64 + i * 16 + quad * 4 + rg;
            float sa = sSqA[rl];
            int   la = sLabA[rl];
#pragma unroll
            for (int j = 0; j < 4; ++j) {
                int   cl = wc * 64 + j * 16 + rr;
                float g  = acc[i][j][rg];
                float d  = fmaxf(sa + sSqB[cl] - 2.0f * g, 0.0f);
                if (la == sLabB[cl]) {
                    posS += d;
                    cnt++;
                } else {
                    float t = 2.0f - sqrtf(d + 1e-9f);
                    if (t > 0.f) negS += t * t;
                }
            }
        }
    }

    const float factor = (bi == bj) ? 1.0f : 2.0f;
    posS *= factor; negS *= factor;

    // wave reduce (64 lanes)
#pragma unroll
    for (int off = 32; off > 0; off >>= 1) {
        posS += __shfl_down(posS, off);
        negS += __shfl_down(negS, off);
        cnt  += __shfl_down(cnt, off);
    }
    if (lane == 0) { rP[wave] = posS; rN[wave] = negS; rC[wave] = cnt; }
    __syncthreads();
    if (tid == 0) {
        float p = rP[0] + rP[1] + rP[2] + rP[3];
        float n = rN[0] + rN[1] + rN[2] + rN[3];
        unsigned int cc = (unsigned int)(rC[0] + rC[1] + rC[2] + rC[3]);
        atomicAdd(posSum, p);
        atomicAdd(negSum, n);
        atomicAdd(posCnt, cc * (unsigned int)factor);
    }
}

// --- kernel 3: combine ---
__global__ void finalize_kernel(const float* __restrict__ posSum,
                                const float* __restrict__ negSum,
                                const unsigned int* __restrict__ posCnt,
                                float* __restrict__ out)
{
    double np = (double)(*posCnt);
    double nn = (double)NPTS * (double)NPTS - np;
    double pt = (np > 0.0) ? 0.5 * (double)(*posSum) / np : 0.0;
    double nt = (nn > 0.0) ? 0.5 * (double)(*negSum) / nn : 0.0;
    out[0] = (float)(pt + nt);
}

extern "C" void kernel_launch(void* const* d_in, const int* in_sizes, int n_in,
                              void* d_out, int out_size, void* d_ws, size_t ws_size,
                              hipStream_t stream) {
    const float* X   = (const float*)d_in[0];
    const int*   lab = (const int*)d_in[1];
    float*       out = (float*)d_out;

    char* ws = (char*)d_ws;
    float*        posSum = (float*)(ws + 0);
    float*        negSum = (float*)(ws + 4);
    unsigned int* posCnt = (unsigned int*)(ws + 8);
    float*        sq     = (float*)(ws + 64);  // 8192 floats = 32 KB

    hipMemsetAsync(ws, 0, 64, stream);
    sq_kernel<<<NPTS / 256, 256, 0, stream>>>(X, sq);

    dim3 grid(64, 64);
    pair_kernel<<<grid, 256, 0, stream>>>(X, lab, sq, posSum, negSum, posCnt);

    finalize_kernel<<<1, 1, 0, stream>>>(posSum, negSum, posCnt, out);
}

// Round 3
// 111.444 us; speedup vs baseline: 1.6579x; 1.6579x over previous
//
#include <hip/hip_runtime.h>
#include <math.h>

#define NPTS 8192
#define DDIM 128
#define LDA  72   // LDS row stride in bf16 elems: 64 data + 8 pad (144B rows, 16B aligned)

using short8 = __attribute__((ext_vector_type(8))) short;
using f32x4  = __attribute__((ext_vector_type(4))) float;

__device__ __forceinline__ unsigned short f2bf(float f) {
    unsigned int u = __float_as_uint(f);
    u += 0x7fffu + ((u >> 16) & 1u);
    return (unsigned short)(u >> 16);
}
__device__ __forceinline__ float bf2f(unsigned short s) {
    return __uint_as_float(((unsigned int)s) << 16);
}

// --- kernel 1: convert X -> bf16 once, and sq[i] = ||bf16(x_i)||^2 ---
// one wave per row; lane handles 2 consecutive floats
__global__ __launch_bounds__(256) void prep_kernel(
    const float* __restrict__ X, unsigned short* __restrict__ Xbf,
    float* __restrict__ sq)
{
    const int wave = threadIdx.x >> 6, lane = threadIdx.x & 63;
    const int row  = blockIdx.x * 4 + wave;
    float2 v = *(const float2*)(X + (size_t)row * DDIM + lane * 2);
    unsigned short a = f2bf(v.x), b = f2bf(v.y);
    float fa = bf2f(a), fb = bf2f(b);
    float s = fa * fa + fb * fb;
    *(ushort2*)(Xbf + (size_t)row * DDIM + lane * 2) = make_ushort2(a, b);
#pragma unroll
    for (int off = 32; off > 0; off >>= 1) s += __shfl_down(s, off);
    if (lane == 0) sq[row] = s;
}

// --- kernel 2: 128x128 Gram tiles via bf16 MFMA, fused loss, slot outputs ---
__global__ __launch_bounds__(256) void pair_kernel(
    const unsigned short* __restrict__ Xbf, const int* __restrict__ lab,
    const float* __restrict__ sq, float* __restrict__ slots /* [3][4096] */)
{
    const int bj = blockIdx.x;  // column block
    const int bi = blockIdx.y;  // row block
    const int slot = bi * 64 + bj;

    if (bj < bi) {              // lower triangle: write zero partials, exit
        if (threadIdx.x == 0) {
            slots[slot] = 0.f; slots[4096 + slot] = 0.f; slots[8192 + slot] = 0.f;
        }
        return;
    }

    __shared__ unsigned short sA[128 * LDA];
    __shared__ unsigned short sB[128 * LDA];
    __shared__ float sSqA[128], sSqB[128];
    __shared__ int   sLabA[128], sLabB[128];
    __shared__ float rP[4], rN[4], rC[4];

    const int tid   = threadIdx.x;
    const int rowA0 = bi * 128;
    const int rowB0 = bj * 128;

    if (tid < 128) {
        sSqA[tid]  = sq[rowA0 + tid];
        sLabA[tid] = lab[rowA0 + tid];
    } else {
        int t = tid - 128;
        sSqB[t]  = sq[rowB0 + t];
        sLabB[t] = lab[rowB0 + t];
    }

    const int wave = tid >> 6, lane = tid & 63;
    const int quad = lane >> 4, rr = lane & 15;
    const int wr = wave >> 1, wc = wave & 1;  // 64x64 quadrant per wave

    f32x4 acc[4][4];
#pragma unroll
    for (int i = 0; i < 4; ++i)
#pragma unroll
        for (int j = 0; j < 4; ++j)
            acc[i][j] = (f32x4){0.f, 0.f, 0.f, 0.f};

    // K = 128 in two chunks of 64, bf16 staging (16B/lane, coalesced)
    for (int c2 = 0; c2 < 2; ++c2) {
        __syncthreads();
#pragma unroll
        for (int i = 0; i < 4; ++i) {
            int g = tid + i * 256;          // 16B-granule index in [0,1024)
            int r = g >> 3, c8 = g & 7;
            short8 v = *(const short8*)(Xbf + (size_t)(rowA0 + r) * DDIM + c2 * 64 + c8 * 8);
            *(short8*)&sA[r * LDA + c8 * 8] = v;
        }
#pragma unroll
        for (int i = 0; i < 4; ++i) {
            int g = tid + i * 256;
            int r = g >> 3, c8 = g & 7;
            short8 v = *(const short8*)(Xbf + (size_t)(rowB0 + r) * DDIM + c2 * 64 + c8 * 8);
            *(short8*)&sB[r * LDA + c8 * 8] = v;
        }
        __syncthreads();

#pragma unroll
        for (int ks = 0; ks < 2; ++ks) {
            short8 a[4], b[4];
#pragma unroll
            for (int t = 0; t < 4; ++t)
                a[t] = *(const short8*)&sA[(wr * 64 + t * 16 + rr) * LDA + ks * 32 + quad * 8];
#pragma unroll
            for (int t = 0; t < 4; ++t)
                b[t] = *(const short8*)&sB[(wc * 64 + t * 16 + rr) * LDA + ks * 32 + quad * 8];
#pragma unroll
            for (int i = 0; i < 4; ++i)
#pragma unroll
                for (int j = 0; j < 4; ++j)
                    acc[i][j] = __builtin_amdgcn_mfma_f32_16x16x32_bf16(a[i], b[j], acc[i][j], 0, 0, 0);
        }
    }

    // epilogue: C/D layout col=lane&15, row=quad*4+reg (verified m89/m91)
    float sb[4]; int lb[4];
#pragma unroll
    for (int j = 0; j < 4; ++j) {
        int cl = wc * 64 + j * 16 + rr;
        sb[j] = sSqB[cl];
        lb[j] = sLabB[cl];
    }

    float posS = 0.f, negS = 0.f, cnt = 0.f;
#pragma unroll
    for (int i = 0; i < 4; ++i) {
#pragma unroll
        for (int rg = 0; rg < 4; ++rg) {
            int   rl = wr * 64 + i * 16 + quad * 4 + rg;
            float sa = sSqA[rl];
            int   la = sLabA[rl];
#pragma unroll
            for (int j = 0; j < 4; ++j) {
                float g = acc[i][j][rg];
                float d = fmaxf(sa + sb[j] - 2.0f * g, 0.0f);
                // hinge only active when d < margin^2 = 4 (t>0 <=> d+eps<4)
                float t = fmaxf(2.0f - sqrtf(d + 1e-9f), 0.f);
                bool same = (la == lb[j]);
                posS += same ? d : 0.f;
                negS += same ? 0.f : t * t;
                cnt  += same ? 1.f : 0.f;
            }
        }
    }

    const float factor = (bi == bj) ? 1.0f : 2.0f;
    posS *= factor; negS *= factor; cnt *= factor;

#pragma unroll
    for (int off = 32; off > 0; off >>= 1) {
        posS += __shfl_down(posS, off);
        negS += __shfl_down(negS, off);
        cnt  += __shfl_down(cnt, off);
    }
    if (lane == 0) { rP[wave] = posS; rN[wave] = negS; rC[wave] = cnt; }
    __syncthreads();
    if (tid == 0) {
        slots[slot]        = rP[0] + rP[1] + rP[2] + rP[3];
        slots[4096 + slot] = rN[0] + rN[1] + rN[2] + rN[3];
        slots[8192 + slot] = rC[0] + rC[1] + rC[2] + rC[3];
    }
}

// --- kernel 3: reduce 4096 slots x 3 and combine ---
__global__ __launch_bounds__(1024) void finalize_kernel(
    const float* __restrict__ slots, float* __restrict__ out)
{
    __shared__ float sP[16], sN[16], sC[16];
    const int tid = threadIdx.x;
    float p = 0.f, n = 0.f, c = 0.f;
#pragma unroll
    for (int k = 0; k < 4; ++k) {
        int i = tid + k * 1024;
        p += slots[i]; n += slots[4096 + i]; c += slots[8192 + i];
    }
#pragma unroll
    for (int off = 32; off > 0; off >>= 1) {
        p += __shfl_down(p, off);
        n += __shfl_down(n, off);
        c += __shfl_down(c, off);
    }
    const int wave = tid >> 6, lane = tid & 63;
    if (lane == 0) { sP[wave] = p; sN[wave] = n; sC[wave] = c; }
    __syncthreads();
    if (tid == 0) {
        float tp = 0.f, tn = 0.f, tc = 0.f;
#pragma unroll
        for (int w = 0; w < 16; ++w) { tp += sP[w]; tn += sN[w]; tc += sC[w]; }
        double np = (double)tc;
        double nn = (double)NPTS * (double)NPTS - np;
        double pt = (np > 0.0) ? 0.5 * (double)tp / np : 0.0;
        double nt = (nn > 0.0) ? 0.5 * (double)tn / nn : 0.0;
        out[0] = (float)(pt + nt);
    }
}

extern "C" void kernel_launch(void* const* d_in, const int* in_sizes, int n_in,
                              void* d_out, int out_size, void* d_ws, size_t ws_size,
                              hipStream_t stream) {
    const float* X   = (const float*)d_in[0];
    const int*   lab = (const int*)d_in[1];
    float*       out = (float*)d_out;

    char* ws = (char*)d_ws;
    unsigned short* Xbf   = (unsigned short*)(ws);                 // 2 MB
    float*          sq    = (float*)(ws + 2 * 1024 * 1024);        // 32 KB
    float*          slots = (float*)(ws + 2 * 1024 * 1024 + 32 * 1024); // 48 KB

    prep_kernel<<<NPTS / 4, 256, 0, stream>>>(X, Xbf, sq);

    dim3 grid(64, 64);
    pair_kernel<<<grid, 256, 0, stream>>>(Xbf, lab, sq, slots);

    finalize_kernel<<<1, 1024, 0, stream>>>(slots, out);
}

// Round 4
// 101.909 us; speedup vs baseline: 1.8131x; 1.0936x over previous
//
#include <hip/hip_runtime.h>
#include <math.h>

#define NPTS   8192
#define DDIM   128
#define NBLK   64            // 8192 / 128 row-blocks
#define NTRI   2080          // NBLK*(NBLK+1)/2 working blocks

using short8 = __attribute__((ext_vector_type(8))) short;
using f32x4  = __attribute__((ext_vector_type(4))) float;

__device__ __forceinline__ unsigned short f2bf(float f) {
    unsigned int u = __float_as_uint(f);
    u += 0x7fffu + ((u >> 16) & 1u);
    return (unsigned short)(u >> 16);
}
__device__ __forceinline__ float bf2f(unsigned short s) {
    return __uint_as_float(((unsigned int)s) << 16);
}

// --- kernel 1: convert X -> bf16 once; sq[i] = ||bf16(x_i)||^2 ---
__global__ __launch_bounds__(256) void prep_kernel(
    const float* __restrict__ X, unsigned short* __restrict__ Xbf,
    float* __restrict__ sq)
{
    const int wave = threadIdx.x >> 6, lane = threadIdx.x & 63;
    const int row  = blockIdx.x * 4 + wave;
    float2 v = *(const float2*)(X + (size_t)row * DDIM + lane * 2);
    unsigned short a = f2bf(v.x), b = f2bf(v.y);
    float fa = bf2f(a), fb = bf2f(b);
    float s = fa * fa + fb * fb;
    *(ushort2*)(Xbf + (size_t)row * DDIM + lane * 2) = make_ushort2(a, b);
#pragma unroll
    for (int off = 32; off > 0; off >>= 1) s += __shfl_down(s, off);
    if (lane == 0) sq[row] = s;
}

// --- kernel 2: barrier-free Gram tiles, fragments loaded straight from L2 ---
// Grid: NTRI linear blocks, decoded to upper-triangle (bi, bj).
// Per block: 128x128 tile; 4 waves each own a 64x64 quadrant; fragments are
// contiguous 16B rows of Xbf -> no LDS staging, no staging barriers.
__global__ __launch_bounds__(256) void pair_kernel(
    const unsigned short* __restrict__ Xbf, const int* __restrict__ lab,
    const float* __restrict__ sq, float* __restrict__ slots /* [2][NTRI] */)
{
    const int k = blockIdx.x;
    // decode: O(b) = 64b - b(b-1)/2 ; bi = floor((129 - sqrt(129^2 - 8k))/2)
    int bi = (int)((129.0f - sqrtf((float)(16641 - 8 * k))) * 0.5f);
    if (bi < 0) bi = 0;
    while (64 * (bi + 1) - ((bi + 1) * bi) / 2 <= k) ++bi;   // O(bi+1) <= k
    while (64 * bi - (bi * (bi - 1)) / 2 > k) --bi;          // O(bi)   >  k
    const int bj = bi + (k - (64 * bi - (bi * (bi - 1)) / 2));

    __shared__ float sSqA[128], sSqB[128];
    __shared__ int   sLabA[128], sLabB[128];
    __shared__ float rP[4], rN[4];

    const int tid   = threadIdx.x;
    const int rowA0 = bi * 128;
    const int rowB0 = bj * 128;

    if (tid < 128) {
        sSqA[tid]  = sq[rowA0 + tid];
        sLabA[tid] = lab[rowA0 + tid];
    } else {
        int t = tid - 128;
        sSqB[t]  = sq[rowB0 + t];
        sLabB[t] = lab[rowB0 + t];
    }
    __syncthreads();   // the only barrier: publish sq/lab for the epilogue

    const int wave = tid >> 6, lane = tid & 63;
    const int quad = lane >> 4, rr = lane & 15;
    const int wr = wave >> 1, wc = wave & 1;

    // fragment base: A[m = rr][k = quad*8 + j] contiguous 8 bf16 = 16B
    const unsigned short* pA = Xbf + (size_t)(rowA0 + wr * 64 + rr) * DDIM + quad * 8;
    const unsigned short* pB = Xbf + (size_t)(rowB0 + wc * 64 + rr) * DDIM + quad * 8;

    f32x4 acc[4][4];
#pragma unroll
    for (int i = 0; i < 4; ++i)
#pragma unroll
        for (int j = 0; j < 4; ++j)
            acc[i][j] = (f32x4){0.f, 0.f, 0.f, 0.f};

#pragma unroll
    for (int kc = 0; kc < 4; ++kc) {    // K = 128 in 4 chunks of 32
        short8 a[4], b[4];
#pragma unroll
        for (int t = 0; t < 4; ++t)
            a[t] = *(const short8*)(pA + t * 16 * DDIM + kc * 32);
#pragma unroll
        for (int t = 0; t < 4; ++t)
            b[t] = *(const short8*)(pB + t * 16 * DDIM + kc * 32);
#pragma unroll
        for (int i = 0; i < 4; ++i)
#pragma unroll
            for (int j = 0; j < 4; ++j)
                acc[i][j] = __builtin_amdgcn_mfma_f32_16x16x32_bf16(a[i], b[j], acc[i][j], 0, 0, 0);
    }

    // epilogue. C/D layout: col = lane&15, row = quad*4 + reg (verified)
    float sb[4]; int lbv[4];
#pragma unroll
    for (int j = 0; j < 4; ++j) {
        int cl = wc * 64 + j * 16 + rr;
        sb[j] = sSqB[cl];
        lbv[j] = sLabB[cl];
    }

    // fast path: pos-sum + min over diff-label distances (hinge active iff d+eps<4)
    float posS = 0.f, dmin = 1e30f;
#pragma unroll
    for (int i = 0; i < 4; ++i) {
#pragma unroll
        for (int rg = 0; rg < 4; ++rg) {
            int   rl = wr * 64 + i * 16 + quad * 4 + rg;
            float sa = sSqA[rl];
            int   la = sLabA[rl];
#pragma unroll
            for (int j = 0; j < 4; ++j) {
                float d = fmaxf(sa + sb[j] - 2.0f * acc[i][j][rg], 0.0f);
                bool same = (la == lbv[j]);
                posS += same ? d : 0.f;
                dmin = fminf(dmin, same ? 1e30f : d);
            }
        }
    }

    float negS = 0.f;
    if (__any(dmin + 1e-9f < 4.0f)) {   // rare: some hinge term is nonzero
#pragma unroll
        for (int i = 0; i < 4; ++i) {
#pragma unroll
            for (int rg = 0; rg < 4; ++rg) {
                int   rl = wr * 64 + i * 16 + quad * 4 + rg;
                float sa = sSqA[rl];
                int   la = sLabA[rl];
#pragma unroll
                for (int j = 0; j < 4; ++j) {
                    float d = fmaxf(sa + sb[j] - 2.0f * acc[i][j][rg], 0.0f);
                    float t = fmaxf(2.0f - sqrtf(d + 1e-9f), 0.f);
                    negS += (la == lbv[j]) ? 0.f : t * t;
                }
            }
        }
    }

    const float factor = (bi == bj) ? 1.0f : 2.0f;
    posS *= factor; negS *= factor;

#pragma unroll
    for (int off = 32; off > 0; off >>= 1) {
        posS += __shfl_down(posS, off);
        negS += __shfl_down(negS, off);
    }
    if (lane == 0) { rP[wave] = posS; rN[wave] = negS; }
    __syncthreads();
    if (tid == 0) {
        slots[k]        = rP[0] + rP[1] + rP[2] + rP[3];
        slots[NTRI + k] = rN[0] + rN[1] + rN[2] + rN[3];
    }
}

// --- kernel 3: label histogram (exact num_pos) + slot reduce + combine ---
__global__ __launch_bounds__(1024) void finalize_kernel(
    const float* __restrict__ slots, const int* __restrict__ lab,
    float* __restrict__ out)
{
    __shared__ int   hist[64];
    __shared__ float sP[16], sN[16];
    const int tid = threadIdx.x;
    if (tid < 64) hist[tid] = 0;
    __syncthreads();
    for (int i = tid; i < NPTS; i += 1024) atomicAdd(&hist[lab[i]], 1);

    float p = 0.f, n = 0.f;
    for (int i = tid; i < NTRI; i += 1024) { p += slots[i]; n += slots[NTRI + i]; }
#pragma unroll
    for (int off = 32; off > 0; off >>= 1) {
        p += __shfl_down(p, off);
        n += __shfl_down(n, off);
    }
    const int wave = tid >> 6, lane = tid & 63;
    if (lane == 0) { sP[wave] = p; sN[wave] = n; }
    __syncthreads();
    if (tid == 0) {
        long long np = 0;
        for (int c = 0; c < 64; ++c) np += (long long)hist[c] * hist[c];
        float tp = 0.f, tn = 0.f;
#pragma unroll
        for (int w = 0; w < 16; ++w) { tp += sP[w]; tn += sN[w]; }
        double dnp = (double)np;
        double dnn = (double)NPTS * (double)NPTS - dnp;
        double pt = (dnp > 0.0) ? 0.5 * (double)tp / dnp : 0.0;
        double nt = (dnn > 0.0) ? 0.5 * (double)tn / dnn : 0.0;
        out[0] = (float)(pt + nt);
    }
}

extern "C" void kernel_launch(void* const* d_in, const int* in_sizes, int n_in,
                              void* d_out, int out_size, void* d_ws, size_t ws_size,
                              hipStream_t stream) {
    const float* X   = (const float*)d_in[0];
    const int*   lab = (const int*)d_in[1];
    float*       out = (float*)d_out;

    char* ws = (char*)d_ws;
    unsigned short* Xbf   = (unsigned short*)(ws);                      // 2 MB
    float*          sq    = (float*)(ws + 2 * 1024 * 1024);             // 32 KB
    float*          slots = (float*)(ws + 2 * 1024 * 1024 + 32 * 1024); // 16.6 KB

    prep_kernel<<<NPTS / 4, 256, 0, stream>>>(X, Xbf, sq);
    pair_kernel<<<NTRI, 256, 0, stream>>>(Xbf, lab, sq, slots);
    finalize_kernel<<<1, 1024, 0, stream>>>(slots, lab, out);
}